// Round 8
// baseline (380.420 us; speedup 1.0000x reference)
//
#include <hip/hip_runtime.h>
#include <hip/hip_bf16.h>
#include <math.h>

// ---------------------------------------------------------------------------
// DeepDCNN: emb-gather -> 4x [grouped full-conv + pair-fold + ordered top-k +
// tanh] -> FC.  All fp32.
// Top-k = wave-level bitwise radix select; ballots via
// __builtin_amdgcn_ballot_w64(cmp) (one v_cmp each).  Two rows per wave,
// interleaved radix chains.  launch_bounds min-waves=2 (VGPR cap 256) keeps
// the key/window register arrays OUT of scratch — R5-R7 ran with VGPR_Count
// 44-48 and silently spilled them (the hidden 3x VALU bloat).
// ---------------------------------------------------------------------------

#if defined(__has_builtin)
#if __has_builtin(__builtin_amdgcn_ballot_w64)
#define BALLOT64(expr) __builtin_amdgcn_ballot_w64(expr)
#endif
#endif
#ifndef BALLOT64
#define BALLOT64(expr) __ballot(expr)
#endif

__device__ __forceinline__ unsigned f2ord(float f) {
    unsigned u = __float_as_uint(f);
    return (u & 0x80000000u) ? ~u : (u | 0x80000000u);
}
// inverse of f2ord
__device__ __forceinline__ float ord2f(unsigned key) {
    unsigned u = (key & 0x80000000u) ? (key & 0x7fffffffu) : ~key;
    return __uint_as_float(u);
}
// tanh via exp + hw rcp: 1 - 2*rcp(e^{2x}+1).  |err| ~1e-7, limits exact.
// Selection keys are pre-tanh so ordering is unaffected.
__device__ __forceinline__ float tanh_fast(float x) {
    float e = __expf(2.f * x);
    return 1.f - 2.f * __builtin_amdgcn_rcpf(e + 1.f);
}
// popcount of ballot bits strictly below this lane
__device__ __forceinline__ int mbcnt64(unsigned long long m) {
    return __builtin_amdgcn_mbcnt_hi((unsigned)(m >> 32),
           __builtin_amdgcn_mbcnt_lo((unsigned)m, 0u));
}

// ---- compaction + tanh + scatter-write of kept elements (one row) --------
// T = exact key of k-th largest; stable (earliest ties kept), order-preserving.
template<int CH>
__device__ __forceinline__ void select_finish(const unsigned* keys, unsigned T,
                                              int k, float* __restrict__ out)
{
    int g = 0, e = 0;
    #pragma unroll
    for (int i = 0; i < CH; ++i) { g += (keys[i] > T); e += (keys[i] == T); }

    int gtBefore = 0, eqBefore = 0, totG = 0;
    #pragma unroll
    for (int b = 0; b < 5; ++b) {     // CH <= 17 < 32 -> 5 bits
        unsigned long long mg = BALLOT64((((g >> b) & 1) != 0));
        unsigned long long me = BALLOT64((((e >> b) & 1) != 0));
        gtBefore += mbcnt64(mg) << b;
        eqBefore += mbcnt64(me) << b;
        totG     += __popcll(mg) << b;
    }
    const int needTies = k - totG;    // # of ==T to keep (earliest)

    int gRun = 0, eRun = 0;
    #pragma unroll
    for (int i = 0; i < CH; ++i) {
        const unsigned key = keys[i];
        const bool isG = key > T;
        const bool isE = key == T;
        const int eIdx = eqBefore + eRun;
        const int dst = gtBefore + gRun + min(eIdx, needTies);
        if (isG || (isE && eIdx < needTies))
            out[dst] = tanh_fast(ord2f(key));
        gRun += isG; eRun += isE;
    }
}

// ---- dual-row exact top-k: two independent radix chains interleaved ------
// Lane holds contiguous chunk [lane*CH, ...) of each row as order-keys in
// regs; invalid slots MUST be 0 (below every real key).
template<int CH>
__device__ void wave_select2(const unsigned* k0, const unsigned* k1, int k,
                             float* __restrict__ out0, float* __restrict__ out1)
{
    unsigned p0 = 0, p1 = 0;
    #pragma unroll 1
    for (int pos = 31; pos >= 0; --pos) {
        const unsigned bit = 1u << pos;
        const unsigned t0 = p0 | bit, t1 = p1 | bit;
        int c0 = 0, c1 = 0;
        #pragma unroll
        for (int i = 0; i < CH; ++i) {
            c0 += __popcll(BALLOT64((k0[i] >= t0)));
            c1 += __popcll(BALLOT64((k1[i] >= t1)));
        }
        if (c0 >= k) p0 = t0;         // wave-uniform (scalar) decisions
        if (c1 >= k) p1 = t1;
    }
    select_finish<CH>(k0, p0, k, out0);
    select_finish<CH>(k1, p1, k, out1);
}

// ---------------------------------------------------------------------------
// Layer 1 fused: emb gather + pair conv (IPG=1,K=7) + fold + select + tanh.
// grid (32 j, 64 b), block 320 = 5 waves; wave w handles filters w and w+5
// (dual interleaved select).  min-waves=2 -> VGPR cap 256, no spill (~110 live).
// ---------------------------------------------------------------------------
__global__ __launch_bounds__(320, 2) void layer1_fused(
    const int* __restrict__ tokens, const float* __restrict__ emb,
    const float* __restrict__ W1, const float* __restrict__ B1,
    float* __restrict__ Z1)
{
    const int j = blockIdx.x;       // 0..31 pair-group
    const int b = blockIdx.y;       // 0..63
    const int t = threadIdx.x;
    const int w = t >> 6;           // 0..4
    const int lane = t & 63;

    __shared__ float xr[2][1036];

    const float2* emb2 = (const float2*)emb;
    for (int i = t; i < 1036; i += 320) {
        int s = i - 6;
        float a = 0.f, c = 0.f;
        if (s >= 0 && s < 1024) {
            int tok = tokens[b * 1024 + s];
            float2 v = emb2[(size_t)tok * 32 + j];
            a = v.x; c = v.y;
        }
        xr[0][i] = a;
        xr[1][i] = c;
    }
    __syncthreads();

    const int beg = lane * 17;
    const int len = max(0, min(17, 1030 - beg));

    float x0[23], x1[23];
    #pragma unroll
    for (int i = 0; i < 23; ++i)
        if (i < len + 6) { x0[i] = xr[0][beg + i]; x1[i] = xr[1][beg + i]; }

    unsigned keys0[17], keys1[17];
    #pragma unroll 2
    for (int half = 0; half < 2; ++half) {
        const int f = w + 5 * half;
        float wa[7], wb[7];
        #pragma unroll
        for (int k2 = 0; k2 < 7; ++k2) {
            wa[k2] = W1[(2 * j * 10 + f) * 7 + k2];
            wb[k2] = W1[((2 * j + 1) * 10 + f) * 7 + k2];
        }
        const float bias = B1[2 * j * 10 + f] + B1[(2 * j + 1) * 10 + f];
        unsigned* keys = half ? keys1 : keys0;
        #pragma unroll
        for (int i = 0; i < 17; ++i) {
            if (i < len) {
                float acc = bias;
                #pragma unroll
                for (int k2 = 0; k2 < 7; ++k2)
                    acc += x0[i + k2] * wa[k2] + x1[i + k2] * wb[k2];
                keys[i] = f2ord(acc);
            } else {
                keys[i] = 0u;
            }
        }
    }
    const size_t orow = (size_t)b * 320 + (size_t)j * 10;
    wave_select2<17>(keys0, keys1, 768,
                     Z1 + (orow + w) * 768,
                     Z1 + (orow + w + 5) * 768);
}

// ---------------------------------------------------------------------------
// Fused conv + fold + select + tanh (layers 2-4).
// grid (G/2 j, 64 b), block NW*64.  Wave w computes output rows (filters)
// f = 2w, 2w+1 completely (length SOUT), then dual-selects top-KSEL of each.
// LDS: all 2*IPG input rows, zero-padded to width 64*CH+K-1 (branchless
// window loads).  Weights are wave-uniform -> scalar s_loads.
// ---------------------------------------------------------------------------
template <int IPG, int NF, int K, int SIN, int SOUT, int KSEL, int NW, int CH>
__global__ __launch_bounds__(NW * 64, 2) void conv_fold_select_kernel(
    const float* __restrict__ X, const float* __restrict__ W,
    const float* __restrict__ Bias, float* __restrict__ Z,
    int Cin, int Cfold)
{
    static_assert(NF == 2 * NW, "2 filters per wave");
    static_assert(64 * CH >= SOUT, "chunk covers row");
    constexpr int W2 = 64 * CH + K - 1;   // padded LDS row width

    const int t = threadIdx.x;
    const int j = blockIdx.x;
    const int b = blockIdx.y;
    const int wav = t >> 6, lane = t & 63;

    __shared__ float xs[2 * IPG][W2];

    const float* Xb = X + ((size_t)b * Cin + (size_t)(2 * j) * IPG) * SIN;
    for (int idx = t; idx < 2 * IPG * W2; idx += NW * 64) {
        int r = idx / W2, p = idx - r * W2;
        int sg = p - (K - 1);
        xs[r][p] = (sg >= 0 && sg < SIN) ? Xb[(size_t)r * SIN + sg] : 0.f;
    }
    __syncthreads();

    const int f0 = __builtin_amdgcn_readfirstlane(2 * wav);
    float acc0[CH], acc1[CH];
    {
        float bias0 = Bias[2 * j * NF + f0]     + Bias[(2 * j + 1) * NF + f0];
        float bias1 = Bias[2 * j * NF + f0 + 1] + Bias[(2 * j + 1) * NF + f0 + 1];
        #pragma unroll
        for (int i = 0; i < CH; ++i) { acc0[i] = bias0; acc1[i] = bias1; }
    }
    const int base = lane * CH;

    #pragma unroll 2
    for (int h = 0; h < 2; ++h) {
        const float* Wh = W + (size_t)((2 * j + h) * NF) * IPG * K;
        #pragma unroll 1
        for (int c = 0; c < IPG; ++c) {
            float win[CH + K - 1];
            #pragma unroll
            for (int p = 0; p < CH + K - 1; ++p)
                win[p] = xs[h * IPG + c][base + p];
            #pragma unroll
            for (int k2 = 0; k2 < K; ++k2) {
                const float w0 = Wh[((size_t)f0 * IPG + c) * K + k2];
                const float w1 = Wh[((size_t)(f0 + 1) * IPG + c) * K + k2];
                #pragma unroll
                for (int i = 0; i < CH; ++i) {
                    acc0[i] = fmaf(win[i + k2], w0, acc0[i]);
                    acc1[i] = fmaf(win[i + k2], w1, acc1[i]);
                }
            }
        }
    }

    unsigned keys0[CH], keys1[CH];
    #pragma unroll
    for (int i = 0; i < CH; ++i) {
        keys0[i] = (base + i < SOUT) ? f2ord(acc0[i]) : 0u;
        keys1[i] = (base + i < SOUT) ? f2ord(acc1[i]) : 0u;
    }
    const size_t orow = (size_t)b * Cfold + (size_t)j * NF;
    wave_select2<CH>(keys0, keys1, KSEL,
                     Z + (orow + f0) * (size_t)KSEL,
                     Z + (orow + f0 + 1) * (size_t)KSEL);
}

// ---------------------------------------------------------------------------
// FC: (64,352) @ (6,352)^T + b
// ---------------------------------------------------------------------------
__global__ __launch_bounds__(192) void fc_kernel(
    const float* __restrict__ Z, const float* __restrict__ Wf,
    const float* __restrict__ bf, float* __restrict__ out)
{
    int g = blockIdx.x * blockDim.x + threadIdx.x;
    if (g >= 64 * 6) return;
    int b = g / 6, c = g % 6;
    float acc = bf[c];
    const float* zr = Z + b * 352;
    const float* wr = Wf + c * 352;
    for (int i = 0; i < 352; ++i) acc += zr[i] * wr[i];
    out[g] = acc;
}

extern "C" void kernel_launch(void* const* d_in, const int* in_sizes, int n_in,
                              void* d_out, int out_size, void* d_ws, size_t ws_size,
                              hipStream_t stream)
{
    const int*   tokens = (const int*)  d_in[0];
    const float* emb    = (const float*)d_in[1];
    const float* w1     = (const float*)d_in[2];
    const float* b1     = (const float*)d_in[3];
    const float* w2     = (const float*)d_in[4];
    const float* b2     = (const float*)d_in[5];
    const float* w3     = (const float*)d_in[6];
    const float* b3     = (const float*)d_in[7];
    const float* w4     = (const float*)d_in[8];
    const float* b4     = (const float*)d_in[9];
    const float* fcw    = (const float*)d_in[10];
    const float* fcb    = (const float*)d_in[11];
    float* out = (float*)d_out;
    float* ws  = (float*)d_ws;

    // workspace layout (floats) — only post-select Z buffers exist:
    //  Z1 [0,        15728640)   64*320*768  (63 MB)
    //  Z2 [15728640, 23068672)   64*224*512  (29 MB)   peak 92 MB
    //  Z3 [0,         2359296)   64*144*256
    //  Z4 [2359296,   2381824)   64*88*4
    float* Z1 = ws;
    float* Z2 = ws + 15728640;
    float* Z3 = ws;
    float* Z4 = ws + 2359296;

    layer1_fused<<<dim3(32, 64), 320, 0, stream>>>(tokens, emb, w1, b1, Z1);

    // L2: IPG=10 NF=14 K=5  768->772, keep 512.  NW=7, CH=13, LDS 65.3 KB
    conv_fold_select_kernel<10, 14, 5, 768, 772, 512, 7, 13>
        <<<dim3(16, 64), 7 * 64, 0, stream>>>(Z1, w2, b2, Z2, 320, 224);

    // L3: IPG=14 NF=18 K=5  512->516, keep 256.  NW=9, CH=9, LDS 63.4 KB
    conv_fold_select_kernel<14, 18, 5, 512, 516, 256, 9, 9>
        <<<dim3(8, 64), 9 * 64, 0, stream>>>(Z2, w3, b3, Z3, 224, 144);

    // L4: IPG=18 NF=22 K=3  256->258, keep 4.    NW=11, CH=5, LDS 45.3 KB
    conv_fold_select_kernel<18, 22, 3, 256, 258, 4, 11, 5>
        <<<dim3(4, 64), 11 * 64, 0, stream>>>(Z3, w4, b4, Z4, 144, 88);

    fc_kernel<<<2, 192, 0, stream>>>(Z4, fcw, fcb, out);
}

// Round 9
// 370.500 us; speedup vs baseline: 1.0268x; 1.0268x over previous
//
#include <hip/hip_runtime.h>
#include <hip/hip_bf16.h>
#include <math.h>

// ---------------------------------------------------------------------------
// DeepDCNN: emb-gather -> 4x [grouped full-conv + pair-fold + ordered top-k +
// tanh] -> FC.  All fp32.
// Top-k = wave-level bitwise radix select (ballot + s_bcnt), with:
//  * EARLY EXIT: stop when bucket == remaining (all bucket members kept) —
//    exact, cuts ~32 -> ~12-16 serial iterations typical.
//  * N interleaved chains per wave (layer1: 5) so independent VALU/SALU
//    bursts overlap (the CU's single shared SALU is the contended pipe).
// ---------------------------------------------------------------------------

#if defined(__has_builtin)
#if __has_builtin(__builtin_amdgcn_ballot_w64)
#define BALLOT64(expr) __builtin_amdgcn_ballot_w64(expr)
#endif
#endif
#ifndef BALLOT64
#define BALLOT64(expr) __ballot(expr)
#endif

__device__ __forceinline__ unsigned f2ord(float f) {
    unsigned u = __float_as_uint(f);
    return (u & 0x80000000u) ? ~u : (u | 0x80000000u);
}
__device__ __forceinline__ float ord2f(unsigned key) {
    unsigned u = (key & 0x80000000u) ? (key & 0x7fffffffu) : ~key;
    return __uint_as_float(u);
}
// tanh via exp + hw rcp: 1 - 2*rcp(e^{2x}+1).  |err| ~1e-7.  Keys are
// pre-tanh so selection ordering is unaffected.
__device__ __forceinline__ float tanh_fast(float x) {
    float e = __expf(2.f * x);
    return 1.f - 2.f * __builtin_amdgcn_rcpf(e + 1.f);
}
__device__ __forceinline__ int mbcnt64(unsigned long long m) {
    return __builtin_amdgcn_mbcnt_hi((unsigned)(m >> 32),
           __builtin_amdgcn_mbcnt_lo((unsigned)m, 0u));
}

// ---- compaction + tanh + scatter-write of kept elements (one row) --------
// T = threshold key (possibly with low bits zeroed by early exit); stable
// (earliest ties kept), order-preserving.
template<int CH>
__device__ __forceinline__ void select_finish(const unsigned* keys, unsigned T,
                                              int k, float* __restrict__ out)
{
    int g = 0, e = 0;
    #pragma unroll
    for (int i = 0; i < CH; ++i) { g += (keys[i] > T); e += (keys[i] == T); }

    int gtBefore = 0, eqBefore = 0, totG = 0;
    #pragma unroll
    for (int b = 0; b < 5; ++b) {     // CH <= 17 < 32 -> 5 bits
        unsigned long long mg = BALLOT64((((g >> b) & 1) != 0));
        unsigned long long me = BALLOT64((((e >> b) & 1) != 0));
        gtBefore += mbcnt64(mg) << b;
        eqBefore += mbcnt64(me) << b;
        totG     += __popcll(mg) << b;
    }
    const int needTies = k - totG;    // # of ==T to keep (earliest)

    int gRun = 0, eRun = 0;
    #pragma unroll
    for (int i = 0; i < CH; ++i) {
        const unsigned key = keys[i];
        const bool isG = key > T;
        const bool isE = key == T;
        const int eIdx = eqBefore + eRun;
        const int dst = gtBefore + gRun + min(eIdx, needTies);
        if (isG || (isE && eIdx < needTies))
            out[dst] = tanh_fast(ord2f(key));
        gRun += isG; eRun += isE;
    }
}

// ---- N-row exact top-k, interleaved radix chains with early exit ---------
// Lane holds contiguous chunk [lane*CH, ...) of each row as order-keys in
// regs; invalid slots MUST be 0 (all finite-float keys are >= 0x00800000).
template<int N, int CH>
__device__ void wave_selectN(const unsigned (*keys)[CH], int k,
                             float* const* outs)
{
    unsigned p[N];
    int above[N], buck[N];
    #pragma unroll
    for (int n = 0; n < N; ++n) { p[n] = 0u; above[n] = 0; buck[n] = 64 * CH; }

    unsigned doneMask = 0;
    const unsigned allDone = (1u << N) - 1u;
    #pragma unroll 1
    for (int pos = 31; pos >= 0; --pos) {
        #pragma unroll
        for (int n = 0; n < N; ++n) {
            if (!((doneMask >> n) & 1u)) {        // wave-uniform branch
                const unsigned t = p[n] | (1u << pos);
                int c = 0;
                #pragma unroll
                for (int i = 0; i < CH; ++i)
                    c += __popcll(BALLOT64((keys[n][i] >= t)));
                const int inb = c - above[n];     // bucket members with bit=1
                const int rem = k - above[n];
                if (inb >= rem) { p[n] = t; buck[n] = inb; }
                else            { above[n] += inb; buck[n] -= inb; }
                if (buck[n] == k - above[n]) doneMask |= (1u << n);
            }
        }
        if (doneMask == allDone) break;
    }
    #pragma unroll
    for (int n = 0; n < N; ++n)
        select_finish<CH>(keys[n], p[n], k, outs[n]);
}

// ---------------------------------------------------------------------------
// Layer 1 fused: emb gather + pair conv (IPG=1,K=7) + fold + select + tanh.
// grid (32 j, 64 b), block 128 = 2 waves; wave w handles filters 5w..5w+4
// as 5 interleaved select chains.
// ---------------------------------------------------------------------------
__global__ __launch_bounds__(128) void layer1_fused(
    const int* __restrict__ tokens, const float* __restrict__ emb,
    const float* __restrict__ W1, const float* __restrict__ B1,
    float* __restrict__ Z1)
{
    const int j = blockIdx.x;       // 0..31 pair-group
    const int b = blockIdx.y;       // 0..63
    const int t = threadIdx.x;
    const int w = t >> 6;           // 0..1
    const int lane = t & 63;

    // padded so every lane's 23-wide window read is in-bounds (lane 63:
    // beg=1071, reads up to 1093 < 1100); pad is zero.
    __shared__ float xr[2][1100];

    const float2* emb2 = (const float2*)emb;
    for (int i = t; i < 1100; i += 128) {
        int s = i - 6;
        float a = 0.f, c = 0.f;
        if (s >= 0 && s < 1024) {
            int tok = tokens[b * 1024 + s];
            float2 v = emb2[(size_t)tok * 32 + j];
            a = v.x; c = v.y;
        }
        xr[0][i] = a;
        xr[1][i] = c;
    }
    __syncthreads();

    const int beg = lane * 17;

    unsigned keys[5][17];
    float* outs[5];
    const size_t orow = (size_t)b * 320 + (size_t)j * 10;

    #pragma unroll
    for (int q = 0; q < 5; ++q) {
        const int f = 5 * w + q;
        float wa[7], wb[7];
        #pragma unroll
        for (int k2 = 0; k2 < 7; ++k2) {
            wa[k2] = W1[(2 * j * 10 + f) * 7 + k2];
            wb[k2] = W1[((2 * j + 1) * 10 + f) * 7 + k2];
        }
        const float bias = B1[2 * j * 10 + f] + B1[(2 * j + 1) * 10 + f];
        #pragma unroll
        for (int i = 0; i < 17; ++i) {
            float acc = bias;
            #pragma unroll
            for (int k2 = 0; k2 < 7; ++k2)
                acc += xr[0][beg + i + k2] * wa[k2]
                     + xr[1][beg + i + k2] * wb[k2];
            keys[q][i] = (beg + i < 1030) ? f2ord(acc) : 0u;
        }
        outs[q] = Z1 + (orow + f) * 768;
    }
    wave_selectN<5, 17>(keys, 768, outs);
}

// ---------------------------------------------------------------------------
// Fused conv + fold + select + tanh (layers 2-4).
// grid (G/2 j, 64 b), block NW*64.  Wave w computes output rows (filters)
// f = 2w, 2w+1 (length SOUT), then dual-chain selects top-KSEL of each.
// LDS: all 2*IPG input rows, zero-padded to width 64*CH+K-1 (branchless
// window loads).  Weights are wave-uniform -> scalar s_loads.
// ---------------------------------------------------------------------------
template <int IPG, int NF, int K, int SIN, int SOUT, int KSEL, int NW, int CH>
__global__ __launch_bounds__(NW * 64) void conv_fold_select_kernel(
    const float* __restrict__ X, const float* __restrict__ W,
    const float* __restrict__ Bias, float* __restrict__ Z,
    int Cin, int Cfold)
{
    static_assert(NF == 2 * NW, "2 filters per wave");
    static_assert(64 * CH >= SOUT, "chunk covers row");
    constexpr int W2 = 64 * CH + K - 1;   // padded LDS row width

    const int t = threadIdx.x;
    const int j = blockIdx.x;
    const int b = blockIdx.y;
    const int wav = t >> 6, lane = t & 63;

    __shared__ float xs[2 * IPG][W2];

    const float* Xb = X + ((size_t)b * Cin + (size_t)(2 * j) * IPG) * SIN;
    for (int idx = t; idx < 2 * IPG * W2; idx += NW * 64) {
        int r = idx / W2, p = idx - r * W2;
        int sg = p - (K - 1);
        xs[r][p] = (sg >= 0 && sg < SIN) ? Xb[(size_t)r * SIN + sg] : 0.f;
    }
    __syncthreads();

    const int f0 = __builtin_amdgcn_readfirstlane(2 * wav);
    float acc0[CH], acc1[CH];
    {
        float bias0 = Bias[2 * j * NF + f0]     + Bias[(2 * j + 1) * NF + f0];
        float bias1 = Bias[2 * j * NF + f0 + 1] + Bias[(2 * j + 1) * NF + f0 + 1];
        #pragma unroll
        for (int i = 0; i < CH; ++i) { acc0[i] = bias0; acc1[i] = bias1; }
    }
    const int base = lane * CH;

    #pragma unroll 2
    for (int h = 0; h < 2; ++h) {
        const float* Wh = W + (size_t)((2 * j + h) * NF) * IPG * K;
        #pragma unroll 1
        for (int c = 0; c < IPG; ++c) {
            float win[CH + K - 1];
            #pragma unroll
            for (int p = 0; p < CH + K - 1; ++p)
                win[p] = xs[h * IPG + c][base + p];
            #pragma unroll
            for (int k2 = 0; k2 < K; ++k2) {
                const float w0 = Wh[((size_t)f0 * IPG + c) * K + k2];
                const float w1 = Wh[((size_t)(f0 + 1) * IPG + c) * K + k2];
                #pragma unroll
                for (int i = 0; i < CH; ++i) {
                    acc0[i] = fmaf(win[i + k2], w0, acc0[i]);
                    acc1[i] = fmaf(win[i + k2], w1, acc1[i]);
                }
            }
        }
    }

    unsigned keys[2][CH];
    #pragma unroll
    for (int i = 0; i < CH; ++i) {
        keys[0][i] = (base + i < SOUT) ? f2ord(acc0[i]) : 0u;
        keys[1][i] = (base + i < SOUT) ? f2ord(acc1[i]) : 0u;
    }
    const size_t orow = (size_t)b * Cfold + (size_t)j * NF;
    float* outs[2] = { Z + (orow + f0) * (size_t)KSEL,
                       Z + (orow + f0 + 1) * (size_t)KSEL };
    wave_selectN<2, CH>(keys, KSEL, outs);
}

// ---------------------------------------------------------------------------
// FC: (64,352) @ (6,352)^T + b
// ---------------------------------------------------------------------------
__global__ __launch_bounds__(192) void fc_kernel(
    const float* __restrict__ Z, const float* __restrict__ Wf,
    const float* __restrict__ bf, float* __restrict__ out)
{
    int g = blockIdx.x * blockDim.x + threadIdx.x;
    if (g >= 64 * 6) return;
    int b = g / 6, c = g % 6;
    float acc = bf[c];
    const float* zr = Z + b * 352;
    const float* wr = Wf + c * 352;
    for (int i = 0; i < 352; ++i) acc += zr[i] * wr[i];
    out[g] = acc;
}

extern "C" void kernel_launch(void* const* d_in, const int* in_sizes, int n_in,
                              void* d_out, int out_size, void* d_ws, size_t ws_size,
                              hipStream_t stream)
{
    const int*   tokens = (const int*)  d_in[0];
    const float* emb    = (const float*)d_in[1];
    const float* w1     = (const float*)d_in[2];
    const float* b1     = (const float*)d_in[3];
    const float* w2     = (const float*)d_in[4];
    const float* b2     = (const float*)d_in[5];
    const float* w3     = (const float*)d_in[6];
    const float* b3     = (const float*)d_in[7];
    const float* w4     = (const float*)d_in[8];
    const float* b4     = (const float*)d_in[9];
    const float* fcw    = (const float*)d_in[10];
    const float* fcb    = (const float*)d_in[11];
    float* out = (float*)d_out;
    float* ws  = (float*)d_ws;

    // workspace layout (floats) — only post-select Z buffers exist:
    //  Z1 [0,        15728640)   64*320*768  (63 MB)
    //  Z2 [15728640, 23068672)   64*224*512  (29 MB)   peak 92 MB
    //  Z3 [0,         2359296)   64*144*256
    //  Z4 [2359296,   2381824)   64*88*4
    float* Z1 = ws;
    float* Z2 = ws + 15728640;
    float* Z3 = ws;
    float* Z4 = ws + 2359296;

    layer1_fused<<<dim3(32, 64), 128, 0, stream>>>(tokens, emb, w1, b1, Z1);

    // L2: IPG=10 NF=14 K=5  768->772, keep 512.  NW=7, CH=13
    conv_fold_select_kernel<10, 14, 5, 768, 772, 512, 7, 13>
        <<<dim3(16, 64), 7 * 64, 0, stream>>>(Z1, w2, b2, Z2, 320, 224);

    // L3: IPG=14 NF=18 K=5  512->516, keep 256.  NW=9, CH=9
    conv_fold_select_kernel<14, 18, 5, 512, 516, 256, 9, 9>
        <<<dim3(8, 64), 9 * 64, 0, stream>>>(Z2, w3, b3, Z3, 224, 144);

    // L4: IPG=18 NF=22 K=3  256->258, keep 4.    NW=11, CH=5
    conv_fold_select_kernel<18, 22, 3, 256, 258, 4, 11, 5>
        <<<dim3(4, 64), 11 * 64, 0, stream>>>(Z3, w4, b4, Z4, 144, 88);

    fc_kernel<<<2, 192, 0, stream>>>(Z4, fcw, fcb, out);
}

// Round 10
// 343.102 us; speedup vs baseline: 1.1088x; 1.0799x over previous
//
#include <hip/hip_runtime.h>
#include <hip/hip_bf16.h>
#include <math.h>

// ---------------------------------------------------------------------------
// DeepDCNN: emb-gather -> 4x [grouped full-conv + pair-fold + ordered top-k +
// tanh] -> FC.  All fp32.
// Top-k = wave-level bitwise radix select (ballot + s_bcnt) with early exit
// and N interleaved chains per wave.  Kept values are staged in a per-wave
// LDS buffer and written out COALESCED (the old per-element scattered
// global_store_dword amplified store transactions ~10x).
// L2 uses two-phase LDS staging (h=0 rows then h=1 rows) to halve xs and
// raise residency 2 -> 3 blocks/CU.
// ---------------------------------------------------------------------------

#if defined(__has_builtin)
#if __has_builtin(__builtin_amdgcn_ballot_w64)
#define BALLOT64(expr) __builtin_amdgcn_ballot_w64(expr)
#endif
#endif
#ifndef BALLOT64
#define BALLOT64(expr) __ballot(expr)
#endif

__device__ __forceinline__ unsigned f2ord(float f) {
    unsigned u = __float_as_uint(f);
    return (u & 0x80000000u) ? ~u : (u | 0x80000000u);
}
__device__ __forceinline__ float ord2f(unsigned key) {
    unsigned u = (key & 0x80000000u) ? (key & 0x7fffffffu) : ~key;
    return __uint_as_float(u);
}
// tanh via exp + hw rcp: 1 - 2*rcp(e^{2x}+1).  |err| ~1e-7.  Keys are
// pre-tanh so selection ordering is unaffected.
__device__ __forceinline__ float tanh_fast(float x) {
    float e = __expf(2.f * x);
    return 1.f - 2.f * __builtin_amdgcn_rcpf(e + 1.f);
}
__device__ __forceinline__ int mbcnt64(unsigned long long m) {
    return __builtin_amdgcn_mbcnt_hi((unsigned)(m >> 32),
           __builtin_amdgcn_mbcnt_lo((unsigned)m, 0u));
}

// ---- compaction + tanh -> LDS stage -> coalesced global write (one row) ---
// T = threshold key; stable (earliest ties kept), order-preserving.
// stage = per-wave LDS buffer of >= k floats.  Same-wave DS ordering makes
// the scatter-write -> contiguous-read sequence safe without barriers.
template<int CH>
__device__ __forceinline__ void select_finish(const unsigned* keys, unsigned T,
                                              int k, float* stage,
                                              float* __restrict__ out)
{
    int g = 0, e = 0;
    #pragma unroll
    for (int i = 0; i < CH; ++i) { g += (keys[i] > T); e += (keys[i] == T); }

    int gtBefore = 0, eqBefore = 0, totG = 0;
    #pragma unroll
    for (int b = 0; b < 5; ++b) {     // CH <= 17 < 32 -> 5 bits
        unsigned long long mg = BALLOT64((((g >> b) & 1) != 0));
        unsigned long long me = BALLOT64((((e >> b) & 1) != 0));
        gtBefore += mbcnt64(mg) << b;
        eqBefore += mbcnt64(me) << b;
        totG     += __popcll(mg) << b;
    }
    const int needTies = k - totG;    // # of ==T to keep (earliest)

    int gRun = 0, eRun = 0;
    #pragma unroll
    for (int i = 0; i < CH; ++i) {
        const unsigned key = keys[i];
        const bool isG = key > T;
        const bool isE = key == T;
        const int eIdx = eqBefore + eRun;
        const int dst = gtBefore + gRun + min(eIdx, needTies);
        if (isG || (isE && eIdx < needTies))
            stage[dst] = tanh_fast(ord2f(key));
        gRun += isG; eRun += isE;
    }
    // coalesced copy-out
    const int lane = threadIdx.x & 63;
    for (int i = lane; i < k; i += 64)
        out[i] = stage[i];
}

// ---- N-row exact top-k, interleaved radix chains with early exit ---------
// Lane holds contiguous chunk [lane*CH, ...) of each row as order-keys in
// regs; invalid slots MUST be 0 (all finite-float keys are >= 0x00800000).
template<int N, int CH>
__device__ void wave_selectN(const unsigned (*keys)[CH], int k, float* stage,
                             float* const* outs)
{
    unsigned p[N];
    int above[N], buck[N];
    #pragma unroll
    for (int n = 0; n < N; ++n) { p[n] = 0u; above[n] = 0; buck[n] = 64 * CH; }

    unsigned doneMask = 0;
    const unsigned allDone = (1u << N) - 1u;
    #pragma unroll 1
    for (int pos = 31; pos >= 0; --pos) {
        #pragma unroll
        for (int n = 0; n < N; ++n) {
            if (!((doneMask >> n) & 1u)) {        // wave-uniform branch
                const unsigned t = p[n] | (1u << pos);
                int c = 0;
                #pragma unroll
                for (int i = 0; i < CH; ++i)
                    c += __popcll(BALLOT64((keys[n][i] >= t)));
                const int inb = c - above[n];     // bucket members with bit=1
                const int rem = k - above[n];
                if (inb >= rem) { p[n] = t; buck[n] = inb; }
                else            { above[n] += inb; buck[n] -= inb; }
                if (buck[n] == k - above[n]) doneMask |= (1u << n);
            }
        }
        if (doneMask == allDone) break;
    }
    #pragma unroll
    for (int n = 0; n < N; ++n)
        select_finish<CH>(keys[n], p[n], k, stage, outs[n]);
}

// ---------------------------------------------------------------------------
// Layer 1 fused: emb gather + pair conv (IPG=1,K=7) + fold + select + tanh.
// grid (32 j, 64 b), block 128 = 2 waves; wave w handles filters 5w..5w+4
// as 5 interleaved select chains.
// ---------------------------------------------------------------------------
__global__ __launch_bounds__(128) void layer1_fused(
    const int* __restrict__ tokens, const float* __restrict__ emb,
    const float* __restrict__ W1, const float* __restrict__ B1,
    float* __restrict__ Z1)
{
    const int j = blockIdx.x;       // 0..31 pair-group
    const int b = blockIdx.y;       // 0..63
    const int t = threadIdx.x;
    const int w = t >> 6;           // 0..1
    const int lane = t & 63;

    // padded so every lane's 23-wide window read is in-bounds; pad is zero.
    __shared__ float xr[2][1100];
    __shared__ float stagebuf[2][768];

    const float2* emb2 = (const float2*)emb;
    for (int i = t; i < 1100; i += 128) {
        int s = i - 6;
        float a = 0.f, c = 0.f;
        if (s >= 0 && s < 1024) {
            int tok = tokens[b * 1024 + s];
            float2 v = emb2[(size_t)tok * 32 + j];
            a = v.x; c = v.y;
        }
        xr[0][i] = a;
        xr[1][i] = c;
    }
    __syncthreads();

    const int beg = lane * 17;

    unsigned keys[5][17];
    float* outs[5];
    const size_t orow = (size_t)b * 320 + (size_t)j * 10;

    #pragma unroll
    for (int q = 0; q < 5; ++q) {
        const int f = 5 * w + q;
        float wa[7], wb[7];
        #pragma unroll
        for (int k2 = 0; k2 < 7; ++k2) {
            wa[k2] = W1[(2 * j * 10 + f) * 7 + k2];
            wb[k2] = W1[((2 * j + 1) * 10 + f) * 7 + k2];
        }
        const float bias = B1[2 * j * 10 + f] + B1[(2 * j + 1) * 10 + f];
        #pragma unroll
        for (int i = 0; i < 17; ++i) {
            float acc = bias;
            #pragma unroll
            for (int k2 = 0; k2 < 7; ++k2)
                acc += xr[0][beg + i + k2] * wa[k2]
                     + xr[1][beg + i + k2] * wb[k2];
            keys[q][i] = (beg + i < 1030) ? f2ord(acc) : 0u;
        }
        outs[q] = Z1 + (orow + f) * 768;
    }
    wave_selectN<5, 17>(keys, 768, stagebuf[w], outs);
}

// ---------------------------------------------------------------------------
// Fused conv + fold + select + tanh (layers 2-4).
// grid (G/2 j, 64 b), block NW*64.  Wave w computes output rows (filters)
// f = 2w, 2w+1 (length SOUT), then dual-chain selects top-KSEL of each.
// PHASES=2: stage h=0 input rows, accumulate, barrier, stage h=1 rows —
// halves xs LDS (raises blocks/CU).  Weights wave-uniform -> s_loads.
// ---------------------------------------------------------------------------
template <int IPG, int NF, int K, int SIN, int SOUT, int KSEL, int NW, int CH,
          int PHASES>
__global__ __launch_bounds__(NW * 64) void conv_fold_select_kernel(
    const float* __restrict__ X, const float* __restrict__ W,
    const float* __restrict__ Bias, float* __restrict__ Z,
    int Cin, int Cfold)
{
    static_assert(NF == 2 * NW, "2 filters per wave");
    static_assert(64 * CH >= SOUT, "chunk covers row");
    constexpr int W2 = 64 * CH + K - 1;     // padded LDS row width
    constexpr int RS = 2 * IPG / PHASES;    // rows staged per phase

    const int t = threadIdx.x;
    const int j = blockIdx.x;
    const int b = blockIdx.y;
    const int wav = t >> 6, lane = t & 63;

    __shared__ float xs[RS][W2];
    __shared__ float stagebuf[NW][KSEL];

    const float* Xb = X + ((size_t)b * Cin + (size_t)(2 * j) * IPG) * SIN;

    const int f0 = __builtin_amdgcn_readfirstlane(2 * wav);
    float acc0[CH], acc1[CH];
    {
        float bias0 = Bias[2 * j * NF + f0]     + Bias[(2 * j + 1) * NF + f0];
        float bias1 = Bias[2 * j * NF + f0 + 1] + Bias[(2 * j + 1) * NF + f0 + 1];
        #pragma unroll
        for (int i = 0; i < CH; ++i) { acc0[i] = bias0; acc1[i] = bias1; }
    }
    const int base = lane * CH;

    #pragma unroll 1
    for (int ph = 0; ph < PHASES; ++ph) {
        if (ph) __syncthreads();            // prior phase's reads done
        for (int idx = t; idx < RS * W2; idx += NW * 64) {
            int r = idx / W2, p = idx - r * W2;
            int sg = p - (K - 1);
            int gr = ph * RS + r;
            xs[r][p] = (sg >= 0 && sg < SIN) ? Xb[(size_t)gr * SIN + sg] : 0.f;
        }
        __syncthreads();

        int h = (ph * RS) / IPG, c = (ph * RS) % IPG;
        #pragma unroll 1
        for (int r = 0; r < RS; ++r) {
            float win[CH + K - 1];
            #pragma unroll
            for (int p = 0; p < CH + K - 1; ++p)
                win[p] = xs[r][base + p];
            const float* Wp = W + ((size_t)((2 * j + h) * NF + f0) * IPG + c) * K;
            #pragma unroll
            for (int k2 = 0; k2 < K; ++k2) {
                const float w0 = Wp[k2];
                const float w1 = Wp[(size_t)IPG * K + k2];
                #pragma unroll
                for (int i = 0; i < CH; ++i) {
                    acc0[i] = fmaf(win[i + k2], w0, acc0[i]);
                    acc1[i] = fmaf(win[i + k2], w1, acc1[i]);
                }
            }
            if (++c == IPG) { c = 0; ++h; }
        }
    }

    unsigned keys[2][CH];
    #pragma unroll
    for (int i = 0; i < CH; ++i) {
        keys[0][i] = (base + i < SOUT) ? f2ord(acc0[i]) : 0u;
        keys[1][i] = (base + i < SOUT) ? f2ord(acc1[i]) : 0u;
    }
    const size_t orow = (size_t)b * Cfold + (size_t)j * NF;
    float* outs[2] = { Z + (orow + f0) * (size_t)KSEL,
                       Z + (orow + f0 + 1) * (size_t)KSEL };
    wave_selectN<2, CH>(keys, KSEL, stagebuf[wav], outs);
}

// ---------------------------------------------------------------------------
// FC: (64,352) @ (6,352)^T + b
// ---------------------------------------------------------------------------
__global__ __launch_bounds__(192) void fc_kernel(
    const float* __restrict__ Z, const float* __restrict__ Wf,
    const float* __restrict__ bf, float* __restrict__ out)
{
    int g = blockIdx.x * blockDim.x + threadIdx.x;
    if (g >= 64 * 6) return;
    int b = g / 6, c = g % 6;
    float acc = bf[c];
    const float* zr = Z + b * 352;
    const float* wr = Wf + c * 352;
    for (int i = 0; i < 352; ++i) acc += zr[i] * wr[i];
    out[g] = acc;
}

extern "C" void kernel_launch(void* const* d_in, const int* in_sizes, int n_in,
                              void* d_out, int out_size, void* d_ws, size_t ws_size,
                              hipStream_t stream)
{
    const int*   tokens = (const int*)  d_in[0];
    const float* emb    = (const float*)d_in[1];
    const float* w1     = (const float*)d_in[2];
    const float* b1     = (const float*)d_in[3];
    const float* w2     = (const float*)d_in[4];
    const float* b2     = (const float*)d_in[5];
    const float* w3     = (const float*)d_in[6];
    const float* b3     = (const float*)d_in[7];
    const float* w4     = (const float*)d_in[8];
    const float* b4     = (const float*)d_in[9];
    const float* fcw    = (const float*)d_in[10];
    const float* fcb    = (const float*)d_in[11];
    float* out = (float*)d_out;
    float* ws  = (float*)d_ws;

    // workspace layout (floats) — only post-select Z buffers exist:
    //  Z1 [0,        15728640)   64*320*768  (63 MB)
    //  Z2 [15728640, 23068672)   64*224*512  (29 MB)   peak 92 MB
    //  Z3 [0,         2359296)   64*144*256
    //  Z4 [2359296,   2381824)   64*88*4
    float* Z1 = ws;
    float* Z2 = ws + 15728640;
    float* Z3 = ws;
    float* Z4 = ws + 2359296;

    layer1_fused<<<dim3(32, 64), 128, 0, stream>>>(tokens, emb, w1, b1, Z1);

    // L2: IPG=10 NF=14 K=5  768->772, keep 512.  NW=7, CH=13, 2-phase LDS
    conv_fold_select_kernel<10, 14, 5, 768, 772, 512, 7, 13, 2>
        <<<dim3(16, 64), 7 * 64, 0, stream>>>(Z1, w2, b2, Z2, 320, 224);

    // L3: IPG=14 NF=18 K=5  512->516, keep 256.  NW=9, CH=9, 1-phase
    conv_fold_select_kernel<14, 18, 5, 512, 516, 256, 9, 9, 1>
        <<<dim3(8, 64), 9 * 64, 0, stream>>>(Z2, w3, b3, Z3, 224, 144);

    // L4: IPG=18 NF=22 K=3  256->258, keep 4.    NW=11, CH=5, 1-phase
    conv_fold_select_kernel<18, 22, 3, 256, 258, 4, 11, 5, 1>
        <<<dim3(4, 64), 11 * 64, 0, stream>>>(Z3, w4, b4, Z4, 144, 88);

    fc_kernel<<<2, 192, 0, stream>>>(Z4, fcw, fcb, out);
}